// Round 10
// baseline (204.160 us; speedup 1.0000x reference)
//
#include <hip/hip_runtime.h>
#include <hip/hip_bf16.h>
#include <math.h>

typedef unsigned short ush;
typedef __attribute__((ext_vector_type(8))) _Float16 fragh;  // 8 fp16 = 4 VGPRs
typedef __attribute__((ext_vector_type(4))) _Float16 half4;
typedef __attribute__((ext_vector_type(4))) float f32x4;

#define S_   1024
#define H_   1024
#define NH_  16
#define D_   64
#define L_   9
#define MB_  (1048576ull)

// async global->LDS, 16B per lane; lds ptr must be wave-uniform base.
__device__ __forceinline__ void load_lds16(const ush* g, const ush* l) {
  __builtin_amdgcn_global_load_lds(
      (const __attribute__((address_space(1))) void*)g,
      (__attribute__((address_space(3))) void*)l, 16, 0, 0);
}

// ---------------------------------------------------------------------------
// prep: ONE dispatch for all input conditioning.
//   blocks [0,2048):    cast x fp32 -> fp16 (xh)
//   blocks [2048,3072): cast+transpose weights W [k][n] fp32 -> WT [n][k] fp16
//                       (flat -> z,y,x of the old (16,16,4) grid)
//   block 3072:         transpose Ws [1024][9] -> WsT [9][1024] fp32
// ---------------------------------------------------------------------------
__global__ __launch_bounds__(256) void prep(
    const float* __restrict__ x,
    const float* W0, const float* W1, const float* W2, const float* W3,
    const float* __restrict__ Ws,
    ush* __restrict__ xh, ush* T0, ush* T1, ush* T2, ush* T3,
    float* __restrict__ WsT) {
  __shared__ __align__(16) float Ls[64][68];
  const int bid = blockIdx.x;
  const int tid = threadIdx.x;

  if (bid < 2048) {                       // ---- x cast ----
    const size_t i = ((size_t)bid * 256 + tid) * 8;
    float4 a = *(const float4*)&x[i];
    float4 b = *(const float4*)&x[i + 4];
    fragh v;
    v[0] = (_Float16)a.x; v[1] = (_Float16)a.y;
    v[2] = (_Float16)a.z; v[3] = (_Float16)a.w;
    v[4] = (_Float16)b.x; v[5] = (_Float16)b.y;
    v[6] = (_Float16)b.z; v[7] = (_Float16)b.w;
    *(fragh*)&xh[i] = v;
    return;
  }
  if (bid >= 3072) {                      // ---- Ws transpose ----
    for (int idx = tid; idx < 1024 * 9; idx += 256) {
      const int r = idx / 9, c = idx - r * 9;
      WsT[c * 1024 + r] = Ws[idx];
    }
    return;
  }
  // ---- weight cast+transpose ----
  const int flat = bid - 2048;
  const int wz = flat >> 8, wy = (flat >> 4) & 15, wx = flat & 15;
  const float* W = (wz == 0) ? W0 : (wz == 1) ? W1 : (wz == 2) ? W2 : W3;
  ush* Th = (wz == 0) ? T0 : (wz == 1) ? T1 : (wz == 2) ? T2 : T3;
  const int n0 = wx * 64, k0 = wy * 64;
#pragma unroll
  for (int it = 0; it < 4; it++) {
    int f = tid + 256 * it;
    int row = f >> 4, nc = (f & 15) * 4;
    *(float4*)&Ls[row][nc] = *(const float4*)&W[(size_t)(k0 + row) * 1024 + n0 + nc];
  }
  __syncthreads();
#pragma unroll
  for (int it = 0; it < 2; it++) {
    int f = tid + 256 * it;
    int nrow = f >> 3, kc = (f & 7) * 8;
    fragh v;
#pragma unroll
    for (int u = 0; u < 8; u++) v[u] = (_Float16)Ls[kc + u][nrow];
    *(fragh*)&Th[(size_t)(n0 + nrow) * 1024 + k0 + kc] = v;
  }
}

// ---------------------------------------------------------------------------
// Fused QKV GEMM, fp16 single-term, 128x128 tile, counted-vmcnt pipeline
// (verified R9; at this shape's structural ceiling -- do not touch).
// Grid (8,32,3) = 768 = 3/CU, LDS 32KB.
// ---------------------------------------------------------------------------
__global__ __launch_bounds__(256) void gemm_qkv(
    const ush* __restrict__ xh,
    const ush* __restrict__ Bq, const ush* __restrict__ Bk,
    const ush* __restrict__ Bv,
    const float* __restrict__ bq, const float* __restrict__ bk,
    const float* __restrict__ bv,
    ush* __restrict__ qh, ush* __restrict__ kh, ush* __restrict__ vT) {
  __shared__ __align__(16) ush As[2][128][32];   // [buf][m][k] fp16 bits
  __shared__ __align__(16) ush Bs[2][128][32];   // [buf][n][k] fp16 bits
  const int tid = threadIdx.x, lane = tid & 63, wave = tid >> 6;
  const int l15 = lane & 15, quad = lane >> 4;
  const int m0 = blockIdx.y * 128, n0 = blockIdx.x * 128;
  const int z = blockIdx.z;
  const ush* Bg = (z == 0) ? Bq : (z == 1) ? Bk : Bv;
  const float* bias = (z == 0) ? bq : (z == 1) ? bk : bv;
  ush* outp = (z == 0) ? qh : (z == 1) ? kh : vT;

  const int wm = (wave >> 1) * 64, wn = (wave & 1) * 64;

  f32x4 acc[4][4];
#pragma unroll
  for (int i = 0; i < 4; i++)
#pragma unroll
    for (int j = 0; j < 4; j++) acc[i][j] = (f32x4){0.f, 0.f, 0.f, 0.f};

  auto stage = [&](int bi, int k0) {
#pragma unroll
    for (int jj = 0; jj < 2; jj++) {
      const int call = wave * 2 + jj;
      const int c = call * 64 + lane;
      const int r = c >> 2, ch = c & 3;
      load_lds16(xh + (size_t)(m0 + r) * 1024 + k0 + ch * 8,
                 &As[bi][0][0] + (size_t)call * 512);
    }
#pragma unroll
    for (int jj = 0; jj < 2; jj++) {
      const int call = wave * 2 + jj;
      const int c = call * 64 + lane;
      const int r = c >> 2, ch = c & 3;
      load_lds16(Bg + (size_t)(n0 + r) * 1024 + k0 + ch * 8,
                 &Bs[bi][0][0] + (size_t)call * 512);
    }
  };

  auto compute = [&](int cur) {
    fragh a[4];
#pragma unroll
    for (int s = 0; s < 4; s++)
      a[s] = *(const fragh*)&As[cur][wm + s * 16 + l15][quad * 8];
#pragma unroll
    for (int t = 0; t < 4; t++) {
      fragh bt = *(const fragh*)&Bs[cur][wn + t * 16 + l15][quad * 8];
#pragma unroll
      for (int mi = 0; mi < 4; mi++)
        acc[mi][t] = __builtin_amdgcn_mfma_f32_16x16x32_f16(
            a[mi], bt, acc[mi][t], 0, 0, 0);
    }
  };

  stage(0, 0);
#pragma unroll 1
  for (int t = 0; t < 31; ++t) {
    const int cur = t & 1;
    stage(cur ^ 1, (t + 1) << 5);
    __builtin_amdgcn_sched_barrier(0);
    asm volatile("s_waitcnt vmcnt(4)" ::: "memory");
    __builtin_amdgcn_sched_barrier(0);
    __builtin_amdgcn_s_barrier();
    compute(cur);
    __builtin_amdgcn_s_barrier();
  }
  __builtin_amdgcn_sched_barrier(0);
  asm volatile("s_waitcnt vmcnt(0)" ::: "memory");
  __builtin_amdgcn_sched_barrier(0);
  __builtin_amdgcn_s_barrier();
  compute(1);

#pragma unroll
  for (int mi = 0; mi < 4; mi++) {
    const int rbase = m0 + wm + mi * 16 + quad * 4;
    const int bb = rbase >> 10, ss = rbase & 1023;
#pragma unroll
    for (int ni = 0; ni < 4; ni++) {
      const int col = n0 + wn + ni * 16 + l15;
      const float bv_ = bias[col];
      const int hidx = col >> 6, d = col & 63;
      if (z == 2) {
        half4 p4;
        p4[0] = (_Float16)(acc[mi][ni][0] + bv_);
        p4[1] = (_Float16)(acc[mi][ni][1] + bv_);
        p4[2] = (_Float16)(acc[mi][ni][2] + bv_);
        p4[3] = (_Float16)(acc[mi][ni][3] + bv_);
        *(half4*)&outp[((size_t)(bb * NH_ + hidx) * D_ + d) * S_ + ss] = p4;
      } else {
#pragma unroll
        for (int r = 0; r < 4; r++) {
          const size_t o =
              ((size_t)(bb * NH_ + hidx) * S_ + (ss + r)) * D_ + d;
          *(_Float16*)&outp[o] = (_Float16)(acc[mi][ni][r] + bv_);
        }
      }
    }
  }
}

// ---------------------------------------------------------------------------
// O-projection GEMM: fp16 single-term, 128x64 tile, counted-vmcnt pipeline.
// Output y now FP16 (rel err 4.9e-4 -> ~6e-4 on logits, vs 0.0078 floor):
// halves the y write + the ln_span read. Grid (16,32) = 512 = 2/CU.
// ---------------------------------------------------------------------------
__global__ __launch_bounds__(256) void gemm_o(
    const ush* __restrict__ ctxh, const ush* __restrict__ Bo,
    const float* __restrict__ bo, const float* __restrict__ resid,
    ush* __restrict__ yh) {
  __shared__ __align__(16) ush As[2][128][32];   // [buf][m][k]
  __shared__ __align__(16) ush Bs[2][64][32];    // [buf][n][k]
  const int tid = threadIdx.x, lane = tid & 63, wave = tid >> 6;
  const int l15 = lane & 15, quad = lane >> 4;
  const int m0 = blockIdx.y * 128, n0 = blockIdx.x * 64;
  const int wm = (wave >> 1) * 64, wn = (wave & 1) * 32;

  f32x4 acc[4][2];
#pragma unroll
  for (int i = 0; i < 4; i++)
#pragma unroll
    for (int j = 0; j < 2; j++) acc[i][j] = (f32x4){0.f, 0.f, 0.f, 0.f};

  auto stage = [&](int bi, int k0) {
#pragma unroll
    for (int jj = 0; jj < 2; jj++) {
      const int call = wave * 2 + jj;
      const int c = call * 64 + lane;
      const int r = c >> 2, ch = c & 3;
      load_lds16(ctxh + (size_t)(m0 + r) * 1024 + k0 + ch * 8,
                 &As[bi][0][0] + (size_t)call * 512);
    }
    {
      const int c = wave * 64 + lane;
      const int r = c >> 2, ch = c & 3;
      load_lds16(Bo + (size_t)(n0 + r) * 1024 + k0 + ch * 8,
                 &Bs[bi][0][0] + (size_t)wave * 512);
    }
  };

  auto compute = [&](int cur) {
    fragh a[4], b[2];
#pragma unroll
    for (int s = 0; s < 4; s++)
      a[s] = *(const fragh*)&As[cur][wm + s * 16 + l15][quad * 8];
#pragma unroll
    for (int t = 0; t < 2; t++)
      b[t] = *(const fragh*)&Bs[cur][wn + t * 16 + l15][quad * 8];
#pragma unroll
    for (int mi = 0; mi < 4; mi++)
#pragma unroll
      for (int ni = 0; ni < 2; ni++)
        acc[mi][ni] = __builtin_amdgcn_mfma_f32_16x16x32_f16(
            a[mi], b[ni], acc[mi][ni], 0, 0, 0);
  };

  stage(0, 0);
#pragma unroll 1
  for (int t = 0; t < 31; ++t) {
    const int cur = t & 1;
    stage(cur ^ 1, (t + 1) << 5);
    __builtin_amdgcn_sched_barrier(0);
    asm volatile("s_waitcnt vmcnt(3)" ::: "memory");
    __builtin_amdgcn_sched_barrier(0);
    __builtin_amdgcn_s_barrier();
    compute(cur);
    __builtin_amdgcn_s_barrier();
  }
  __builtin_amdgcn_sched_barrier(0);
  asm volatile("s_waitcnt vmcnt(0)" ::: "memory");
  __builtin_amdgcn_sched_barrier(0);
  __builtin_amdgcn_s_barrier();
  compute(1);

#pragma unroll
  for (int mi = 0; mi < 4; mi++) {
    const int rbase = m0 + wm + mi * 16 + quad * 4;
#pragma unroll
    for (int ni = 0; ni < 2; ni++) {
      const int col = n0 + wn + ni * 16 + l15;
      const float bv_ = bo[col];
#pragma unroll
      for (int r = 0; r < 4; r++) {
        const int m = rbase + r;
        const float val =
            acc[mi][ni][r] + bv_ + resid[(size_t)m * 1024 + col];
        *(_Float16*)&yh[(size_t)m * 1024 + col] = (_Float16)val;
      }
    }
  }
}

// ---------------------------------------------------------------------------
// MFMA flash attention, fp16 (verified R7): window |j0-q0| <= 128, LDS-LUT
// softmax with fixed shift M=2, fp16 P/ctx. + s_setprio(1) around MFMA
// clusters (T5: multi-block CU, phase-diverse waves). LDS ~28KB -> 4/CU.
// ---------------------------------------------------------------------------
__global__ __launch_bounds__(256) void attn2(
    const ush* __restrict__ qh, const ush* __restrict__ kh,
    const ush* __restrict__ vT, ush* __restrict__ ch) {
  __shared__ __align__(16) ush Kh[64][72];
  __shared__ __align__(16) ush VTs[64][72];   // [d][j]
  __shared__ __align__(16) ush Pst[64][72];   // [m][j]
  __shared__ float LUT[256];
  const int tid = threadIdx.x;
  const int lane = tid & 63, wave = tid >> 6;
  const int l15 = lane & 15, quad = lane >> 4;
  const int w16 = wave * 16;
  const int bh = blockIdx.y;
  const int b = bh >> 4, h = bh & 15;
  const int q0 = blockIdx.x * 64;

  const float K1 = 0.18033688011112042f;   // 0.125 * log2(e)
  const float K2 = 0.14426950408889634f;   // 0.1   * log2(e)
  {
    const float dd = (float)tid;
    LUT[tid] = __expf(-0.1f * fminf(dd, 5.0f)) * K1 - dd * K2
             - 2.8853900817779268f;        // 2*log2(e): fixed shift M=2
  }

  const size_t qrow = ((size_t)bh * S_ + q0 + w16 + l15) * D_;
  fragh a_h[2];
  a_h[0] = *(const fragh*)&qh[qrow + quad * 8];
  a_h[1] = *(const fragh*)&qh[qrow + 32 + quad * 8];

  f32x4 o[4];
  float lrow[4];
#pragma unroll
  for (int i = 0; i < 4; i++) {
    o[i] = (f32x4){0.f, 0.f, 0.f, 0.f};
    lrow[i] = 0.f;
  }

  const size_t kbase = (size_t)bh * S_ * D_;
  const size_t vbase = (size_t)bh * D_ * S_;

  const int jlo = (q0 > 128) ? q0 - 128 : 0;
  const int jend = (q0 + 192 < S_) ? q0 + 192 : S_;

  for (int j0 = jlo; j0 < jend; j0 += 64) {
    __syncthreads();   // prior tile's frag reads done (also fences LUT)
#pragma unroll
    for (int it = 0; it < 2; it++) {
      const int flat = tid + 256 * it;
      const int row = flat >> 3, dc = (flat & 7) * 8;
      *(uint4*)&Kh[row][dc] =
          *(const uint4*)&kh[kbase + (size_t)(j0 + row) * D_ + dc];
      *(uint4*)&VTs[row][dc] =
          *(const uint4*)&vT[vbase + (size_t)row * S_ + j0 + dc];
    }
    __syncthreads();

    // ---- S = Q.K^T (single fp16 term) ----
    f32x4 c4[4];
#pragma unroll
    for (int nt = 0; nt < 4; nt++) c4[nt] = (f32x4){0.f, 0.f, 0.f, 0.f};
    __builtin_amdgcn_s_setprio(1);
#pragma unroll
    for (int kk = 0; kk < 2; kk++) {
#pragma unroll
      for (int nt = 0; nt < 4; nt++) {
        fragh bh_ = *(const fragh*)&Kh[nt * 16 + l15][kk * 32 + quad * 8];
        c4[nt] = __builtin_amdgcn_mfma_f32_16x16x32_f16(a_h[kk], bh_, c4[nt], 0, 0, 0);
      }
    }
    __builtin_amdgcn_s_setprio(0);

    // ---- LUT softmax + P store (C-layout: row=quad*4+r) ----
    const int ib = q0 + w16 + quad * 4 - j0 - l15;
#pragma unroll
    for (int r = 0; r < 4; r++) {
#pragma unroll
      for (int nt = 0; nt < 4; nt++) {
        int di = ib + r - nt * 16;
        di = (di < 0) ? -di : di;
        const float sv = exp2f(fmaf(c4[nt][r], K1, LUT[di]));
        lrow[r] += sv;
        *(_Float16*)&Pst[w16 + quad * 4 + r][nt * 16 + l15] = (_Float16)sv;
      }
    }

    // ---- PV (own rows only; same-wave LDS ordering, no barrier) ----
    fragh pa[2];
    pa[0] = *(const fragh*)&Pst[w16 + l15][quad * 8];
    pa[1] = *(const fragh*)&Pst[w16 + l15][32 + quad * 8];
    __builtin_amdgcn_s_setprio(1);
#pragma unroll
    for (int dt = 0; dt < 4; dt++) {
      fragh vb0 = *(const fragh*)&VTs[dt * 16 + l15][quad * 8];
      fragh vb1 = *(const fragh*)&VTs[dt * 16 + l15][32 + quad * 8];
      o[dt] = __builtin_amdgcn_mfma_f32_16x16x32_f16(pa[0], vb0, o[dt], 0, 0, 0);
      o[dt] = __builtin_amdgcn_mfma_f32_16x16x32_f16(pa[1], vb1, o[dt], 0, 0, 0);
    }
    __builtin_amdgcn_s_setprio(0);
  }

  // ---- deferred row-sum reduction + normalize + write fp16 ctx ----
#pragma unroll
  for (int r = 0; r < 4; r++) {
#pragma unroll
    for (int off = 1; off < 16; off <<= 1) lrow[r] += __shfl_xor(lrow[r], off);
    const float inv = 1.0f / lrow[r];
    const size_t rowp =
        ((size_t)(b * S_ + q0 + w16 + quad * 4 + r)) * H_ + h * 64;
#pragma unroll
    for (int dt = 0; dt < 4; dt++)
      *(_Float16*)&ch[rowp + dt * 16 + l15] = (_Float16)(o[dt][r] * inv);
  }
}

// ---------------------------------------------------------------------------
// Fused LayerNorm + span logits, wave-per-row (no barriers): 4 rows/block,
// lane owns 16 contiguous cols (2x half8 y loads). Logit dots use the
// pre-transposed WsT [9][1024] with float4 loads (36 vector loads vs 144
// scalar strided in the old block-per-row version). Grid 1024 x 256.
// ---------------------------------------------------------------------------
__global__ __launch_bounds__(256) void ln_span(
    const ush* __restrict__ yh, const float* __restrict__ g,
    const float* __restrict__ bta, const float* __restrict__ WsT,
    const float* __restrict__ bs, float* __restrict__ logits) {
  const int tid = threadIdx.x, lane = tid & 63, wave = tid >> 6;
  const int row = blockIdx.x * 4 + wave;
  const int h0 = lane * 16;
  const ush* yr = yh + (size_t)row * 1024 + h0;

  fragh v0 = *(const fragh*)yr;
  fragh v1 = *(const fragh*)(yr + 8);
  float v[16];
#pragma unroll
  for (int u = 0; u < 8; u++) { v[u] = (float)v0[u]; v[8 + u] = (float)v1[u]; }

  float s = 0.f, s2 = 0.f;
#pragma unroll
  for (int u = 0; u < 16; u++) { s += v[u]; s2 += v[u] * v[u]; }
#pragma unroll
  for (int off = 32; off; off >>= 1) {
    s += __shfl_xor(s, off);
    s2 += __shfl_xor(s2, off);
  }
  const float mu = s * (1.0f / 1024.0f);
  const float var = s2 * (1.0f / 1024.0f) - mu * mu;
  const float inv = rsqrtf(var + 1e-5f);

  float yn[16];
#pragma unroll
  for (int i = 0; i < 4; i++) {
    float4 gg = *(const float4*)&g[h0 + i * 4];
    float4 bb = *(const float4*)&bta[h0 + i * 4];
    yn[i * 4 + 0] = (v[i * 4 + 0] - mu) * inv * gg.x + bb.x;
    yn[i * 4 + 1] = (v[i * 4 + 1] - mu) * inv * gg.y + bb.y;
    yn[i * 4 + 2] = (v[i * 4 + 2] - mu) * inv * gg.z + bb.z;
    yn[i * 4 + 3] = (v[i * 4 + 3] - mu) * inv * gg.w + bb.w;
  }

  float lg[9];
#pragma unroll
  for (int l = 0; l < 9; l++) {
    float acc = 0.f;
#pragma unroll
    for (int i = 0; i < 4; i++) {
      float4 w4 = *(const float4*)&WsT[l * 1024 + h0 + i * 4];
      acc += yn[i * 4 + 0] * w4.x + yn[i * 4 + 1] * w4.y +
             yn[i * 4 + 2] * w4.z + yn[i * 4 + 3] * w4.w;
    }
    lg[l] = acc;
  }
#pragma unroll
  for (int l = 0; l < 9; l++) {
#pragma unroll
    for (int off = 32; off; off >>= 1) lg[l] += __shfl_xor(lg[l], off);
  }
  if (lane == 0) {
#pragma unroll
    for (int l = 0; l < 9; l++)
      logits[(size_t)row * 9 + l] = lg[l] + bs[l];
  }
}

// ---------------------------------------------------------------------------
// Entity-bias adjustment + FP32 output. One thread per token.
// ---------------------------------------------------------------------------
__global__ __launch_bounds__(256) void final_kernel(
    const float* __restrict__ logits, const float* __restrict__ eb,
    float* __restrict__ out) {
  const int m = blockIdx.x * 256 + threadIdx.x;
  const int i = m & 1023;
  float cur[9];
#pragma unroll
  for (int l = 0; l < 9; l++) cur[l] = logits[(size_t)m * 9 + l];
  if (i > 0) {
    const float* prev = logits + (size_t)(m - 1) * 9;
    int am = 0;
    float best = prev[0];
#pragma unroll
    for (int l = 1; l < 9; l++) {
      float pv = prev[l];
      if (pv > best) { best = pv; am = l; }
    }
    if (am == 1) cur[2] += 2.0f * eb[2];
  }
#pragma unroll
  for (int l = 0; l < 9; l++) out[(size_t)m * 9 + l] = cur[l];
}

// ---------------------------------------------------------------------------
extern "C" void kernel_launch(void* const* d_in, const int* in_sizes, int n_in,
                              void* d_out, int out_size, void* d_ws, size_t ws_size,
                              hipStream_t stream) {
  const float* x    = (const float*)d_in[0];
  const float* Wq   = (const float*)d_in[1];
  const float* bq   = (const float*)d_in[2];
  const float* Wk   = (const float*)d_in[3];
  const float* bk   = (const float*)d_in[4];
  const float* Wv   = (const float*)d_in[5];
  const float* bv   = (const float*)d_in[6];
  const float* Wo   = (const float*)d_in[7];
  const float* bo   = (const float*)d_in[8];
  const float* ln_g = (const float*)d_in[9];
  const float* ln_b = (const float*)d_in[10];
  const float* Ws   = (const float*)d_in[11];
  const float* bs   = (const float*)d_in[12];
  const float* eb   = (const float*)d_in[13];
  float* out = (float*)d_out;
  char* W8 = (char*)d_ws;

  // ---- ws layout (fp16 everywhere; 64 MB envelope) ----
  // [0,2): WoT  [2,4): WqT  [4,6): WkT  [6,8): WvT
  // [8,16): xh   [16,24): qh  [24,32): kh  [32,40): vT
  // [40,48): ctxh  [48,56): yh fp16  [56,57): lg_ws  [60,~60.04): WsT
  ush* WoT  = (ush*)(W8 + 0 * MB_);
  ush* WqT  = (ush*)(W8 + 2 * MB_);
  ush* WkT  = (ush*)(W8 + 4 * MB_);
  ush* WvT  = (ush*)(W8 + 6 * MB_);
  ush* xh   = (ush*)(W8 + 8 * MB_);
  ush* qh   = (ush*)(W8 + 16 * MB_);
  ush* kh   = (ush*)(W8 + 24 * MB_);
  ush* vT   = (ush*)(W8 + 32 * MB_);
  ush* ctxh = (ush*)(W8 + 40 * MB_);
  ush* yh   = (ush*)(W8 + 48 * MB_);
  float* lg_ws = (float*)(W8 + 56 * MB_);
  float* WsT   = (float*)(W8 + 60 * MB_);

  // all input conditioning in one dispatch (3073 blocks)
  prep<<<3073, 256, 0, stream>>>(
      x, Wq, Wk, Wv, Wo, Ws, xh, WqT, WkT, WvT, WoT, WsT);

  // Q+K+V fused: 768 blocks = 3/CU, 32KB LDS, counted-vmcnt pipeline.
  gemm_qkv<<<dim3(8, 32, 3), 256, 0, stream>>>(
      xh, WqT, WkT, WvT, bq, bk, bv, qh, kh, vT);
  attn2<<<dim3(16, 64), 256, 0, stream>>>(qh, kh, vT, ctxh);
  gemm_o<<<dim3(16, 32), 256, 0, stream>>>(ctxh, WoT, bo, x, yh);
  ln_span<<<1024, 256, 0, stream>>>(yh, ln_g, ln_b, WsT, bs, lg_ws);
  final_kernel<<<16, 256, 0, stream>>>(lg_ws, eb, out);
}

// Round 11
// 198.500 us; speedup vs baseline: 1.0285x; 1.0285x over previous
//
#include <hip/hip_runtime.h>
#include <hip/hip_bf16.h>
#include <math.h>

typedef unsigned short ush;
typedef __attribute__((ext_vector_type(8))) _Float16 fragh;  // 8 fp16 = 4 VGPRs
typedef __attribute__((ext_vector_type(4))) _Float16 half4;
typedef __attribute__((ext_vector_type(4))) float f32x4;

#define S_   1024
#define H_   1024
#define NH_  16
#define D_   64
#define L_   9
#define MB_  (1048576ull)

// async global->LDS, 16B per lane; lds ptr must be wave-uniform base.
__device__ __forceinline__ void load_lds16(const ush* g, const ush* l) {
  __builtin_amdgcn_global_load_lds(
      (const __attribute__((address_space(1))) void*)g,
      (__attribute__((address_space(3))) void*)l, 16, 0, 0);
}

// ---------------------------------------------------------------------------
// prep: ONE dispatch for all input conditioning. (verified R10)
//   blocks [0,2048):    cast x fp32 -> fp16 (xh)
//   blocks [2048,3072): cast+transpose weights W [k][n] fp32 -> WT [n][k] fp16
//   block 3072:         transpose Ws [1024][9] -> WsT [9][1024] fp32
// ---------------------------------------------------------------------------
__global__ __launch_bounds__(256) void prep(
    const float* __restrict__ x,
    const float* W0, const float* W1, const float* W2, const float* W3,
    const float* __restrict__ Ws,
    ush* __restrict__ xh, ush* T0, ush* T1, ush* T2, ush* T3,
    float* __restrict__ WsT) {
  __shared__ __align__(16) float Ls[64][68];
  const int bid = blockIdx.x;
  const int tid = threadIdx.x;

  if (bid < 2048) {                       // ---- x cast ----
    const size_t i = ((size_t)bid * 256 + tid) * 8;
    float4 a = *(const float4*)&x[i];
    float4 b = *(const float4*)&x[i + 4];
    fragh v;
    v[0] = (_Float16)a.x; v[1] = (_Float16)a.y;
    v[2] = (_Float16)a.z; v[3] = (_Float16)a.w;
    v[4] = (_Float16)b.x; v[5] = (_Float16)b.y;
    v[6] = (_Float16)b.z; v[7] = (_Float16)b.w;
    *(fragh*)&xh[i] = v;
    return;
  }
  if (bid >= 3072) {                      // ---- Ws transpose ----
    for (int idx = tid; idx < 1024 * 9; idx += 256) {
      const int r = idx / 9, c = idx - r * 9;
      WsT[c * 1024 + r] = Ws[idx];
    }
    return;
  }
  // ---- weight cast+transpose ----
  const int flat = bid - 2048;
  const int wz = flat >> 8, wy = (flat >> 4) & 15, wx = flat & 15;
  const float* W = (wz == 0) ? W0 : (wz == 1) ? W1 : (wz == 2) ? W2 : W3;
  ush* Th = (wz == 0) ? T0 : (wz == 1) ? T1 : (wz == 2) ? T2 : T3;
  const int n0 = wx * 64, k0 = wy * 64;
#pragma unroll
  for (int it = 0; it < 4; it++) {
    int f = tid + 256 * it;
    int row = f >> 4, nc = (f & 15) * 4;
    *(float4*)&Ls[row][nc] = *(const float4*)&W[(size_t)(k0 + row) * 1024 + n0 + nc];
  }
  __syncthreads();
#pragma unroll
  for (int it = 0; it < 2; it++) {
    int f = tid + 256 * it;
    int nrow = f >> 3, kc = (f & 7) * 8;
    fragh v;
#pragma unroll
    for (int u = 0; u < 8; u++) v[u] = (_Float16)Ls[kc + u][nrow];
    *(fragh*)&Th[(size_t)(n0 + nrow) * 1024 + k0 + kc] = v;
  }
}

// ---------------------------------------------------------------------------
// Fused QKV GEMM, fp16 single-term, 128x128 tile, counted-vmcnt pipeline
// (verified R9; three schedule experiments pinned it at ~43us -- frozen).
// Grid (8,32,3) = 768 = 3/CU, LDS 32KB.
// ---------------------------------------------------------------------------
__global__ __launch_bounds__(256) void gemm_qkv(
    const ush* __restrict__ xh,
    const ush* __restrict__ Bq, const ush* __restrict__ Bk,
    const ush* __restrict__ Bv,
    const float* __restrict__ bq, const float* __restrict__ bk,
    const float* __restrict__ bv,
    ush* __restrict__ qh, ush* __restrict__ kh, ush* __restrict__ vT) {
  __shared__ __align__(16) ush As[2][128][32];   // [buf][m][k] fp16 bits
  __shared__ __align__(16) ush Bs[2][128][32];   // [buf][n][k] fp16 bits
  const int tid = threadIdx.x, lane = tid & 63, wave = tid >> 6;
  const int l15 = lane & 15, quad = lane >> 4;
  const int m0 = blockIdx.y * 128, n0 = blockIdx.x * 128;
  const int z = blockIdx.z;
  const ush* Bg = (z == 0) ? Bq : (z == 1) ? Bk : Bv;
  const float* bias = (z == 0) ? bq : (z == 1) ? bk : bv;
  ush* outp = (z == 0) ? qh : (z == 1) ? kh : vT;

  const int wm = (wave >> 1) * 64, wn = (wave & 1) * 64;

  f32x4 acc[4][4];
#pragma unroll
  for (int i = 0; i < 4; i++)
#pragma unroll
    for (int j = 0; j < 4; j++) acc[i][j] = (f32x4){0.f, 0.f, 0.f, 0.f};

  auto stage = [&](int bi, int k0) {
#pragma unroll
    for (int jj = 0; jj < 2; jj++) {
      const int call = wave * 2 + jj;
      const int c = call * 64 + lane;
      const int r = c >> 2, ch = c & 3;
      load_lds16(xh + (size_t)(m0 + r) * 1024 + k0 + ch * 8,
                 &As[bi][0][0] + (size_t)call * 512);
    }
#pragma unroll
    for (int jj = 0; jj < 2; jj++) {
      const int call = wave * 2 + jj;
      const int c = call * 64 + lane;
      const int r = c >> 2, ch = c & 3;
      load_lds16(Bg + (size_t)(n0 + r) * 1024 + k0 + ch * 8,
                 &Bs[bi][0][0] + (size_t)call * 512);
    }
  };

  auto compute = [&](int cur) {
    fragh a[4];
#pragma unroll
    for (int s = 0; s < 4; s++)
      a[s] = *(const fragh*)&As[cur][wm + s * 16 + l15][quad * 8];
#pragma unroll
    for (int t = 0; t < 4; t++) {
      fragh bt = *(const fragh*)&Bs[cur][wn + t * 16 + l15][quad * 8];
#pragma unroll
      for (int mi = 0; mi < 4; mi++)
        acc[mi][t] = __builtin_amdgcn_mfma_f32_16x16x32_f16(
            a[mi], bt, acc[mi][t], 0, 0, 0);
    }
  };

  stage(0, 0);
#pragma unroll 1
  for (int t = 0; t < 31; ++t) {
    const int cur = t & 1;
    stage(cur ^ 1, (t + 1) << 5);
    __builtin_amdgcn_sched_barrier(0);
    asm volatile("s_waitcnt vmcnt(4)" ::: "memory");
    __builtin_amdgcn_sched_barrier(0);
    __builtin_amdgcn_s_barrier();
    compute(cur);
    __builtin_amdgcn_s_barrier();
  }
  __builtin_amdgcn_sched_barrier(0);
  asm volatile("s_waitcnt vmcnt(0)" ::: "memory");
  __builtin_amdgcn_sched_barrier(0);
  __builtin_amdgcn_s_barrier();
  compute(1);

#pragma unroll
  for (int mi = 0; mi < 4; mi++) {
    const int rbase = m0 + wm + mi * 16 + quad * 4;
    const int bb = rbase >> 10, ss = rbase & 1023;
#pragma unroll
    for (int ni = 0; ni < 4; ni++) {
      const int col = n0 + wn + ni * 16 + l15;
      const float bv_ = bias[col];
      const int hidx = col >> 6, d = col & 63;
      if (z == 2) {
        half4 p4;
        p4[0] = (_Float16)(acc[mi][ni][0] + bv_);
        p4[1] = (_Float16)(acc[mi][ni][1] + bv_);
        p4[2] = (_Float16)(acc[mi][ni][2] + bv_);
        p4[3] = (_Float16)(acc[mi][ni][3] + bv_);
        *(half4*)&outp[((size_t)(bb * NH_ + hidx) * D_ + d) * S_ + ss] = p4;
      } else {
#pragma unroll
        for (int r = 0; r < 4; r++) {
          const size_t o =
              ((size_t)(bb * NH_ + hidx) * S_ + (ss + r)) * D_ + d;
          *(_Float16*)&outp[o] = (_Float16)(acc[mi][ni][r] + bv_);
        }
      }
    }
  }
}

// ---------------------------------------------------------------------------
// O-projection GEMM: fp16 single-term, 128x64 tile, SUPERSTEP pipeline:
// two BK=32 slabs per barrier pair (16 supersteps instead of 32 -- halves
// the per-step fixed cost: vmcnt wait + 2 barriers -- which dominates at
// only 8 MFMA/wave/step). 6 loads/wave/superstep -> vmcnt(6). LDS 48KB,
// grid (16,32) = 512 = 2/CU (grid-limited; no occupancy loss).
// Accumulation order unchanged -> bit-identical to R10.
// ---------------------------------------------------------------------------
__global__ __launch_bounds__(256) void gemm_o(
    const ush* __restrict__ ctxh, const ush* __restrict__ Bo,
    const float* __restrict__ bo, const float* __restrict__ resid,
    ush* __restrict__ yh) {
  __shared__ __align__(16) ush As[2][2][128][32];   // [buf][slab][m][k]
  __shared__ __align__(16) ush Bs[2][2][64][32];    // [buf][slab][n][k]
  const int tid = threadIdx.x, lane = tid & 63, wave = tid >> 6;
  const int l15 = lane & 15, quad = lane >> 4;
  const int m0 = blockIdx.y * 128, n0 = blockIdx.x * 64;
  const int wm = (wave >> 1) * 64, wn = (wave & 1) * 32;

  f32x4 acc[4][2];
#pragma unroll
  for (int i = 0; i < 4; i++)
#pragma unroll
    for (int j = 0; j < 2; j++) acc[i][j] = (f32x4){0.f, 0.f, 0.f, 0.f};

  // 6 global_load_lds per wave per superstep (A: 2 slabs x 2, B: 2 slabs x 1)
  auto stage = [&](int bi, int k0) {
#pragma unroll
    for (int jj = 0; jj < 4; jj++) {
      const int slab = jj >> 1;
      const int cw = wave * 2 + (jj & 1);
      const int c = cw * 64 + lane;        // [0,512)
      const int r = c >> 2, ch = c & 3;
      load_lds16(ctxh + (size_t)(m0 + r) * 1024 + k0 + slab * 32 + ch * 8,
                 &As[bi][slab][0][0] + (size_t)cw * 512);
    }
#pragma unroll
    for (int jj = 0; jj < 2; jj++) {
      const int slab = jj;
      const int c = wave * 64 + lane;      // [0,256)
      const int r = c >> 2, ch = c & 3;
      load_lds16(Bo + (size_t)(n0 + r) * 1024 + k0 + slab * 32 + ch * 8,
                 &Bs[bi][slab][0][0] + (size_t)wave * 512);
    }
  };

  auto compute = [&](int bi) {
#pragma unroll
    for (int slab = 0; slab < 2; slab++) {
      fragh a[4], b[2];
#pragma unroll
      for (int s = 0; s < 4; s++)
        a[s] = *(const fragh*)&As[bi][slab][wm + s * 16 + l15][quad * 8];
#pragma unroll
      for (int t = 0; t < 2; t++)
        b[t] = *(const fragh*)&Bs[bi][slab][wn + t * 16 + l15][quad * 8];
#pragma unroll
      for (int mi = 0; mi < 4; mi++)
#pragma unroll
        for (int ni = 0; ni < 2; ni++)
          acc[mi][ni] = __builtin_amdgcn_mfma_f32_16x16x32_f16(
              a[mi], b[ni], acc[mi][ni], 0, 0, 0);
    }
  };

  stage(0, 0);
#pragma unroll 1
  for (int t = 0; t < 15; ++t) {
    const int cur = t & 1;
    stage(cur ^ 1, (t + 1) << 6);
    __builtin_amdgcn_sched_barrier(0);
    asm volatile("s_waitcnt vmcnt(6)" ::: "memory");
    __builtin_amdgcn_sched_barrier(0);
    __builtin_amdgcn_s_barrier();
    compute(cur);
    __builtin_amdgcn_s_barrier();
  }
  __builtin_amdgcn_sched_barrier(0);
  asm volatile("s_waitcnt vmcnt(0)" ::: "memory");
  __builtin_amdgcn_sched_barrier(0);
  __builtin_amdgcn_s_barrier();
  compute(1);

#pragma unroll
  for (int mi = 0; mi < 4; mi++) {
    const int rbase = m0 + wm + mi * 16 + quad * 4;
#pragma unroll
    for (int ni = 0; ni < 2; ni++) {
      const int col = n0 + wn + ni * 16 + l15;
      const float bv_ = bo[col];
#pragma unroll
      for (int r = 0; r < 4; r++) {
        const int m = rbase + r;
        const float val =
            acc[mi][ni][r] + bv_ + resid[(size_t)m * 1024 + col];
        *(_Float16*)&yh[(size_t)m * 1024 + col] = (_Float16)val;
      }
    }
  }
}

// ---------------------------------------------------------------------------
// MFMA flash attention, fp16, window |j0-q0| <= 128, LDS-LUT softmax
// (fixed shift M=2) + T14 ASYNC-STAGE: next K/V tile loaded into registers
// while the current tile computes; ds_write lands after the barrier. The
// compiler's vmcnt wait falls at the register rotate AFTER compute, so
// QK^T+softmax+PV covers the L2/HBM latency. Math unchanged (bit-identical).
// +32 VGPR for the in-flight tile; launch_bounds(256,4) keeps 4 blocks/CU.
// ---------------------------------------------------------------------------
__global__ __launch_bounds__(256, 4) void attn2(
    const ush* __restrict__ qh, const ush* __restrict__ kh,
    const ush* __restrict__ vT, ush* __restrict__ ch) {
  __shared__ __align__(16) ush Kh[64][72];
  __shared__ __align__(16) ush VTs[64][72];   // [d][j]
  __shared__ __align__(16) ush Pst[64][72];   // [m][j]
  __shared__ float LUT[256];
  const int tid = threadIdx.x;
  const int lane = tid & 63, wave = tid >> 6;
  const int l15 = lane & 15, quad = lane >> 4;
  const int w16 = wave * 16;
  const int bh = blockIdx.y;
  const int b = bh >> 4, h = bh & 15;
  const int q0 = blockIdx.x * 64;

  const float K1 = 0.18033688011112042f;   // 0.125 * log2(e)
  const float K2 = 0.14426950408889634f;   // 0.1   * log2(e)
  {
    const float dd = (float)tid;
    LUT[tid] = __expf(-0.1f * fminf(dd, 5.0f)) * K1 - dd * K2
             - 2.8853900817779268f;        // 2*log2(e): fixed shift M=2
  }

  const size_t qrow = ((size_t)bh * S_ + q0 + w16 + l15) * D_;
  fragh a_h[2];
  a_h[0] = *(const fragh*)&qh[qrow + quad * 8];
  a_h[1] = *(const fragh*)&qh[qrow + 32 + quad * 8];

  f32x4 o[4];
  float lrow[4];
#pragma unroll
  for (int i = 0; i < 4; i++) {
    o[i] = (f32x4){0.f, 0.f, 0.f, 0.f};
    lrow[i] = 0.f;
  }

  const size_t kbase = (size_t)bh * S_ * D_;
  const size_t vbase = (size_t)bh * D_ * S_;

  const int jlo = (q0 > 128) ? q0 - 128 : 0;
  const int jend = (q0 + 192 < S_) ? q0 + 192 : S_;

  // per-thread staging slots (2 iterations of the old loop)
  const int row0 = tid >> 3, dc0 = (tid & 7) * 8;
  const int row1 = (tid + 256) >> 3, dc1 = (tid & 7) * 8;

  uint4 kA0, kA1, vA0, vA1;
  uint4 kB0 = {0, 0, 0, 0}, kB1 = {0, 0, 0, 0};
  uint4 vB0 = {0, 0, 0, 0}, vB1 = {0, 0, 0, 0};
  // prologue: load first tile into registers
  kA0 = *(const uint4*)&kh[kbase + (size_t)(jlo + row0) * D_ + dc0];
  kA1 = *(const uint4*)&kh[kbase + (size_t)(jlo + row1) * D_ + dc1];
  vA0 = *(const uint4*)&vT[vbase + (size_t)row0 * S_ + jlo + dc0];
  vA1 = *(const uint4*)&vT[vbase + (size_t)row1 * S_ + jlo + dc1];

  for (int j0 = jlo; j0 < jend; j0 += 64) {
    __syncthreads();   // prev tile's frag reads done (also fences LUT fill)
    *(uint4*)&Kh[row0][dc0] = kA0;
    *(uint4*)&Kh[row1][dc1] = kA1;
    *(uint4*)&VTs[row0][dc0] = vA0;
    *(uint4*)&VTs[row1][dc1] = vA1;
    const int jn = j0 + 64;
    if (jn < jend) {   // async prefetch next tile into registers
      kB0 = *(const uint4*)&kh[kbase + (size_t)(jn + row0) * D_ + dc0];
      kB1 = *(const uint4*)&kh[kbase + (size_t)(jn + row1) * D_ + dc1];
      vB0 = *(const uint4*)&vT[vbase + (size_t)row0 * S_ + jn + dc0];
      vB1 = *(const uint4*)&vT[vbase + (size_t)row1 * S_ + jn + dc1];
    }
    __syncthreads();

    // ---- S = Q.K^T (single fp16 term) ----
    f32x4 c4[4];
#pragma unroll
    for (int nt = 0; nt < 4; nt++) c4[nt] = (f32x4){0.f, 0.f, 0.f, 0.f};
    __builtin_amdgcn_s_setprio(1);
#pragma unroll
    for (int kk = 0; kk < 2; kk++) {
#pragma unroll
      for (int nt = 0; nt < 4; nt++) {
        fragh bh_ = *(const fragh*)&Kh[nt * 16 + l15][kk * 32 + quad * 8];
        c4[nt] = __builtin_amdgcn_mfma_f32_16x16x32_f16(a_h[kk], bh_, c4[nt], 0, 0, 0);
      }
    }
    __builtin_amdgcn_s_setprio(0);

    // ---- LUT softmax + P store (C-layout: row=quad*4+r) ----
    const int ib = q0 + w16 + quad * 4 - j0 - l15;
#pragma unroll
    for (int r = 0; r < 4; r++) {
#pragma unroll
      for (int nt = 0; nt < 4; nt++) {
        int di = ib + r - nt * 16;
        di = (di < 0) ? -di : di;
        const float sv = exp2f(fmaf(c4[nt][r], K1, LUT[di]));
        lrow[r] += sv;
        *(_Float16*)&Pst[w16 + quad * 4 + r][nt * 16 + l15] = (_Float16)sv;
      }
    }

    // ---- PV (own rows only; same-wave LDS ordering, no barrier) ----
    fragh pa[2];
    pa[0] = *(const fragh*)&Pst[w16 + l15][quad * 8];
    pa[1] = *(const fragh*)&Pst[w16 + l15][32 + quad * 8];
    __builtin_amdgcn_s_setprio(1);
#pragma unroll
    for (int dt = 0; dt < 4; dt++) {
      fragh vb0 = *(const fragh*)&VTs[dt * 16 + l15][quad * 8];
      fragh vb1 = *(const fragh*)&VTs[dt * 16 + l15][32 + quad * 8];
      o[dt] = __builtin_amdgcn_mfma_f32_16x16x32_f16(pa[0], vb0, o[dt], 0, 0, 0);
      o[dt] = __builtin_amdgcn_mfma_f32_16x16x32_f16(pa[1], vb1, o[dt], 0, 0, 0);
    }
    __builtin_amdgcn_s_setprio(0);

    // rotate prefetched tile (vmcnt wait lands here, after compute)
    kA0 = kB0; kA1 = kB1; vA0 = vB0; vA1 = vB1;
  }

  // ---- deferred row-sum reduction + normalize + write fp16 ctx ----
#pragma unroll
  for (int r = 0; r < 4; r++) {
#pragma unroll
    for (int off = 1; off < 16; off <<= 1) lrow[r] += __shfl_xor(lrow[r], off);
    const float inv = 1.0f / lrow[r];
    const size_t rowp =
        ((size_t)(b * S_ + q0 + w16 + quad * 4 + r)) * H_ + h * 64;
#pragma unroll
    for (int dt = 0; dt < 4; dt++)
      *(_Float16*)&ch[rowp + dt * 16 + l15] = (_Float16)(o[dt][r] * inv);
  }
}

// ---------------------------------------------------------------------------
// Fused LayerNorm + span logits, wave-per-row (no barriers). (verified R10)
// ---------------------------------------------------------------------------
__global__ __launch_bounds__(256) void ln_span(
    const ush* __restrict__ yh, const float* __restrict__ g,
    const float* __restrict__ bta, const float* __restrict__ WsT,
    const float* __restrict__ bs, float* __restrict__ logits) {
  const int tid = threadIdx.x, lane = tid & 63, wave = tid >> 6;
  const int row = blockIdx.x * 4 + wave;
  const int h0 = lane * 16;
  const ush* yr = yh + (size_t)row * 1024 + h0;

  fragh v0 = *(const fragh*)yr;
  fragh v1 = *(const fragh*)(yr + 8);
  float v[16];
#pragma unroll
  for (int u = 0; u < 8; u++) { v[u] = (float)v0[u]; v[8 + u] = (float)v1[u]; }

  float s = 0.f, s2 = 0.f;
#pragma unroll
  for (int u = 0; u < 16; u++) { s += v[u]; s2 += v[u] * v[u]; }
#pragma unroll
  for (int off = 32; off; off >>= 1) {
    s += __shfl_xor(s, off);
    s2 += __shfl_xor(s2, off);
  }
  const float mu = s * (1.0f / 1024.0f);
  const float var = s2 * (1.0f / 1024.0f) - mu * mu;
  const float inv = rsqrtf(var + 1e-5f);

  float yn[16];
#pragma unroll
  for (int i = 0; i < 4; i++) {
    float4 gg = *(const float4*)&g[h0 + i * 4];
    float4 bb = *(const float4*)&bta[h0 + i * 4];
    yn[i * 4 + 0] = (v[i * 4 + 0] - mu) * inv * gg.x + bb.x;
    yn[i * 4 + 1] = (v[i * 4 + 1] - mu) * inv * gg.y + bb.y;
    yn[i * 4 + 2] = (v[i * 4 + 2] - mu) * inv * gg.z + bb.z;
    yn[i * 4 + 3] = (v[i * 4 + 3] - mu) * inv * gg.w + bb.w;
  }

  float lg[9];
#pragma unroll
  for (int l = 0; l < 9; l++) {
    float acc = 0.f;
#pragma unroll
    for (int i = 0; i < 4; i++) {
      float4 w4 = *(const float4*)&WsT[l * 1024 + h0 + i * 4];
      acc += yn[i * 4 + 0] * w4.x + yn[i * 4 + 1] * w4.y +
             yn[i * 4 + 2] * w4.z + yn[i * 4 + 3] * w4.w;
    }
    lg[l] = acc;
  }
#pragma unroll
  for (int l = 0; l < 9; l++) {
#pragma unroll
    for (int off = 32; off; off >>= 1) lg[l] += __shfl_xor(lg[l], off);
  }
  if (lane == 0) {
#pragma unroll
    for (int l = 0; l < 9; l++)
      logits[(size_t)row * 9 + l] = lg[l] + bs[l];
  }
}

// ---------------------------------------------------------------------------
// Entity-bias adjustment + FP32 output. One thread per token.
// ---------------------------------------------------------------------------
__global__ __launch_bounds__(256) void final_kernel(
    const float* __restrict__ logits, const float* __restrict__ eb,
    float* __restrict__ out) {
  const int m = blockIdx.x * 256 + threadIdx.x;
  const int i = m & 1023;
  float cur[9];
#pragma unroll
  for (int l = 0; l < 9; l++) cur[l] = logits[(size_t)m * 9 + l];
  if (i > 0) {
    const float* prev = logits + (size_t)(m - 1) * 9;
    int am = 0;
    float best = prev[0];
#pragma unroll
    for (int l = 1; l < 9; l++) {
      float pv = prev[l];
      if (pv > best) { best = pv; am = l; }
    }
    if (am == 1) cur[2] += 2.0f * eb[2];
  }
#pragma unroll
  for (int l = 0; l < 9; l++) out[(size_t)m * 9 + l] = cur[l];
}

// ---------------------------------------------------------------------------
extern "C" void kernel_launch(void* const* d_in, const int* in_sizes, int n_in,
                              void* d_out, int out_size, void* d_ws, size_t ws_size,
                              hipStream_t stream) {
  const float* x    = (const float*)d_in[0];
  const float* Wq   = (const float*)d_in[1];
  const float* bq   = (const float*)d_in[2];
  const float* Wk   = (const float*)d_in[3];
  const float* bk   = (const float*)d_in[4];
  const float* Wv   = (const float*)d_in[5];
  const float* bv   = (const float*)d_in[6];
  const float* Wo   = (const float*)d_in[7];
  const float* bo   = (const float*)d_in[8];
  const float* ln_g = (const float*)d_in[9];
  const float* ln_b = (const float*)d_in[10];
  const float* Ws   = (const float*)d_in[11];
  const float* bs   = (const float*)d_in[12];
  const float* eb   = (const float*)d_in[13];
  float* out = (float*)d_out;
  char* W8 = (char*)d_ws;

  // ---- ws layout (fp16 everywhere; 64 MB envelope) ----
  ush* WoT  = (ush*)(W8 + 0 * MB_);
  ush* WqT  = (ush*)(W8 + 2 * MB_);
  ush* WkT  = (ush*)(W8 + 4 * MB_);
  ush* WvT  = (ush*)(W8 + 6 * MB_);
  ush* xh   = (ush*)(W8 + 8 * MB_);
  ush* qh   = (ush*)(W8 + 16 * MB_);
  ush* kh   = (ush*)(W8 + 24 * MB_);
  ush* vT   = (ush*)(W8 + 32 * MB_);
  ush* ctxh = (ush*)(W8 + 40 * MB_);
  ush* yh   = (ush*)(W8 + 48 * MB_);
  float* lg_ws = (float*)(W8 + 56 * MB_);
  float* WsT   = (float*)(W8 + 60 * MB_);

  prep<<<3073, 256, 0, stream>>>(
      x, Wq, Wk, Wv, Wo, Ws, xh, WqT, WkT, WvT, WoT, WsT);

  gemm_qkv<<<dim3(8, 32, 3), 256, 0, stream>>>(
      xh, WqT, WkT, WvT, bq, bk, bv, qh, kh, vT);
  attn2<<<dim3(16, 64), 256, 0, stream>>>(qh, kh, vT, ctxh);
  gemm_o<<<dim3(16, 32), 256, 0, stream>>>(ctxh, WoT, bo, x, yh);
  ln_span<<<1024, 256, 0, stream>>>(yh, ln_g, ln_b, WsT, bs, lg_ws);
  final_kernel<<<16, 256, 0, stream>>>(lg_ws, eb, out);
}

// Round 14
// 196.047 us; speedup vs baseline: 1.0414x; 1.0125x over previous
//
#include <hip/hip_runtime.h>
#include <hip/hip_bf16.h>
#include <math.h>

typedef unsigned short ush;
typedef __attribute__((ext_vector_type(8))) _Float16 fragh;  // 8 fp16 = 4 VGPRs
typedef __attribute__((ext_vector_type(4))) _Float16 half4;
typedef __attribute__((ext_vector_type(4))) float f32x4;

#define S_   1024
#define H_   1024
#define NH_  16
#define D_   64
#define L_   9
#define MB_  (1048576ull)

// async global->LDS, 16B per lane; lds ptr must be wave-uniform base.
__device__ __forceinline__ void load_lds16(const ush* g, const ush* l) {
  __builtin_amdgcn_global_load_lds(
      (const __attribute__((address_space(1))) void*)g,
      (__attribute__((address_space(3))) void*)l, 16, 0, 0);
}

// ---------------------------------------------------------------------------
// prep: ONE dispatch for all input conditioning. (verified R10)
//   blocks [0,2048):    cast x fp32 -> fp16 (xh)
//   blocks [2048,3072): cast+transpose weights W [k][n] fp32 -> WT [n][k] fp16
//   block 3072:         transpose Ws [1024][9] -> WsT [9][1024] fp32
// ---------------------------------------------------------------------------
__global__ __launch_bounds__(256) void prep(
    const float* __restrict__ x,
    const float* W0, const float* W1, const float* W2, const float* W3,
    const float* __restrict__ Ws,
    ush* __restrict__ xh, ush* T0, ush* T1, ush* T2, ush* T3,
    float* __restrict__ WsT) {
  __shared__ __align__(16) float Ls[64][68];
  const int bid = blockIdx.x;
  const int tid = threadIdx.x;

  if (bid < 2048) {                       // ---- x cast ----
    const size_t i = ((size_t)bid * 256 + tid) * 8;
    float4 a = *(const float4*)&x[i];
    float4 b = *(const float4*)&x[i + 4];
    fragh v;
    v[0] = (_Float16)a.x; v[1] = (_Float16)a.y;
    v[2] = (_Float16)a.z; v[3] = (_Float16)a.w;
    v[4] = (_Float16)b.x; v[5] = (_Float16)b.y;
    v[6] = (_Float16)b.z; v[7] = (_Float16)b.w;
    *(fragh*)&xh[i] = v;
    return;
  }
  if (bid >= 3072) {                      // ---- Ws transpose ----
    for (int idx = tid; idx < 1024 * 9; idx += 256) {
      const int r = idx / 9, c = idx - r * 9;
      WsT[c * 1024 + r] = Ws[idx];
    }
    return;
  }
  // ---- weight cast+transpose ----
  const int flat = bid - 2048;
  const int wz = flat >> 8, wy = (flat >> 4) & 15, wx = flat & 15;
  const float* W = (wz == 0) ? W0 : (wz == 1) ? W1 : (wz == 2) ? W2 : W3;
  ush* Th = (wz == 0) ? T0 : (wz == 1) ? T1 : (wz == 2) ? T2 : T3;
  const int n0 = wx * 64, k0 = wy * 64;
#pragma unroll
  for (int it = 0; it < 4; it++) {
    int f = tid + 256 * it;
    int row = f >> 4, nc = (f & 15) * 4;
    *(float4*)&Ls[row][nc] = *(const float4*)&W[(size_t)(k0 + row) * 1024 + n0 + nc];
  }
  __syncthreads();
#pragma unroll
  for (int it = 0; it < 2; it++) {
    int f = tid + 256 * it;
    int nrow = f >> 3, kc = (f & 7) * 8;
    fragh v;
#pragma unroll
    for (int u = 0; u < 8; u++) v[u] = (_Float16)Ls[kc + u][nrow];
    *(fragh*)&Th[(size_t)(n0 + nrow) * 1024 + k0 + kc] = v;
  }
}

// ---------------------------------------------------------------------------
// Fused QKV GEMM, fp16 single-term, 128x128 tile, counted-vmcnt pipeline
// (verified R9/R11 at 43us; depth-2 variant failed the harness twice in
// R12/R13 and is retired -- this is the verified depth-1 loop, frozen).
// Grid (8,32,3) = 768 = 3/CU, LDS 32KB.
// ---------------------------------------------------------------------------
__global__ __launch_bounds__(256) void gemm_qkv(
    const ush* __restrict__ xh,
    const ush* __restrict__ Bq, const ush* __restrict__ Bk,
    const ush* __restrict__ Bv,
    const float* __restrict__ bq, const float* __restrict__ bk,
    const float* __restrict__ bv,
    ush* __restrict__ qh, ush* __restrict__ kh, ush* __restrict__ vT) {
  __shared__ __align__(16) ush As[2][128][32];   // [buf][m][k] fp16 bits
  __shared__ __align__(16) ush Bs[2][128][32];   // [buf][n][k] fp16 bits
  const int tid = threadIdx.x, lane = tid & 63, wave = tid >> 6;
  const int l15 = lane & 15, quad = lane >> 4;
  const int m0 = blockIdx.y * 128, n0 = blockIdx.x * 128;
  const int z = blockIdx.z;
  const ush* Bg = (z == 0) ? Bq : (z == 1) ? Bk : Bv;
  const float* bias = (z == 0) ? bq : (z == 1) ? bk : bv;
  ush* outp = (z == 0) ? qh : (z == 1) ? kh : vT;

  const int wm = (wave >> 1) * 64, wn = (wave & 1) * 64;

  f32x4 acc[4][4];
#pragma unroll
  for (int i = 0; i < 4; i++)
#pragma unroll
    for (int j = 0; j < 4; j++) acc[i][j] = (f32x4){0.f, 0.f, 0.f, 0.f};

  // 4 global_load_lds per wave per stage (A:2 + B:2)
  auto stage = [&](int bi, int k0) {
#pragma unroll
    for (int jj = 0; jj < 2; jj++) {
      const int call = wave * 2 + jj;
      const int c = call * 64 + lane;
      const int r = c >> 2, ch = c & 3;
      load_lds16(xh + (size_t)(m0 + r) * 1024 + k0 + ch * 8,
                 &As[bi][0][0] + (size_t)call * 512);
    }
#pragma unroll
    for (int jj = 0; jj < 2; jj++) {
      const int call = wave * 2 + jj;
      const int c = call * 64 + lane;
      const int r = c >> 2, ch = c & 3;
      load_lds16(Bg + (size_t)(n0 + r) * 1024 + k0 + ch * 8,
                 &Bs[bi][0][0] + (size_t)call * 512);
    }
  };

  auto compute = [&](int cur) {
    fragh a[4];
#pragma unroll
    for (int s = 0; s < 4; s++)
      a[s] = *(const fragh*)&As[cur][wm + s * 16 + l15][quad * 8];
#pragma unroll
    for (int t = 0; t < 4; t++) {
      fragh bt = *(const fragh*)&Bs[cur][wn + t * 16 + l15][quad * 8];
#pragma unroll
      for (int mi = 0; mi < 4; mi++)
        acc[mi][t] = __builtin_amdgcn_mfma_f32_16x16x32_f16(
            a[mi], bt, acc[mi][t], 0, 0, 0);
    }
  };

  stage(0, 0);
#pragma unroll 1
  for (int t = 0; t < 31; ++t) {
    const int cur = t & 1;
    stage(cur ^ 1, (t + 1) << 5);
    __builtin_amdgcn_sched_barrier(0);
    asm volatile("s_waitcnt vmcnt(4)" ::: "memory");
    __builtin_amdgcn_sched_barrier(0);
    __builtin_amdgcn_s_barrier();
    compute(cur);
    __builtin_amdgcn_s_barrier();
  }
  __builtin_amdgcn_sched_barrier(0);
  asm volatile("s_waitcnt vmcnt(0)" ::: "memory");
  __builtin_amdgcn_sched_barrier(0);
  __builtin_amdgcn_s_barrier();
  compute(1);

#pragma unroll
  for (int mi = 0; mi < 4; mi++) {
    const int rbase = m0 + wm + mi * 16 + quad * 4;
    const int bb = rbase >> 10, ss = rbase & 1023;
#pragma unroll
    for (int ni = 0; ni < 4; ni++) {
      const int col = n0 + wn + ni * 16 + l15;
      const float bv_ = bias[col];
      const int hidx = col >> 6, d = col & 63;
      if (z == 2) {
        half4 p4;
        p4[0] = (_Float16)(acc[mi][ni][0] + bv_);
        p4[1] = (_Float16)(acc[mi][ni][1] + bv_);
        p4[2] = (_Float16)(acc[mi][ni][2] + bv_);
        p4[3] = (_Float16)(acc[mi][ni][3] + bv_);
        *(half4*)&outp[((size_t)(bb * NH_ + hidx) * D_ + d) * S_ + ss] = p4;
      } else {
#pragma unroll
        for (int r = 0; r < 4; r++) {
          const size_t o =
              ((size_t)(bb * NH_ + hidx) * S_ + (ss + r)) * D_ + d;
          *(_Float16*)&outp[o] = (_Float16)(acc[mi][ni][r] + bv_);
        }
      }
    }
  }
}

// ---------------------------------------------------------------------------
// O-projection GEMM: fp16 single-term, 128x64 tile, SUPERSTEP pipeline
// (verified R11): two BK=32 slabs per barrier pair, 6 loads/wave ->
// vmcnt(6). LDS 48KB, grid (16,32) = 512 = 2/CU.
// ---------------------------------------------------------------------------
__global__ __launch_bounds__(256) void gemm_o(
    const ush* __restrict__ ctxh, const ush* __restrict__ Bo,
    const float* __restrict__ bo, const float* __restrict__ resid,
    ush* __restrict__ yh) {
  __shared__ __align__(16) ush As[2][2][128][32];   // [buf][slab][m][k]
  __shared__ __align__(16) ush Bs[2][2][64][32];    // [buf][slab][n][k]
  const int tid = threadIdx.x, lane = tid & 63, wave = tid >> 6;
  const int l15 = lane & 15, quad = lane >> 4;
  const int m0 = blockIdx.y * 128, n0 = blockIdx.x * 64;
  const int wm = (wave >> 1) * 64, wn = (wave & 1) * 32;

  f32x4 acc[4][2];
#pragma unroll
  for (int i = 0; i < 4; i++)
#pragma unroll
    for (int j = 0; j < 2; j++) acc[i][j] = (f32x4){0.f, 0.f, 0.f, 0.f};

  // 6 global_load_lds per wave per superstep (A: 2 slabs x 2, B: 2 slabs x 1)
  auto stage = [&](int bi, int k0) {
#pragma unroll
    for (int jj = 0; jj < 4; jj++) {
      const int slab = jj >> 1;
      const int cw = wave * 2 + (jj & 1);
      const int c = cw * 64 + lane;        // [0,512)
      const int r = c >> 2, ch = c & 3;
      load_lds16(ctxh + (size_t)(m0 + r) * 1024 + k0 + slab * 32 + ch * 8,
                 &As[bi][slab][0][0] + (size_t)cw * 512);
    }
#pragma unroll
    for (int jj = 0; jj < 2; jj++) {
      const int slab = jj;
      const int c = wave * 64 + lane;      // [0,256)
      const int r = c >> 2, ch = c & 3;
      load_lds16(Bo + (size_t)(n0 + r) * 1024 + k0 + slab * 32 + ch * 8,
                 &Bs[bi][slab][0][0] + (size_t)wave * 512);
    }
  };

  auto compute = [&](int bi) {
#pragma unroll
    for (int slab = 0; slab < 2; slab++) {
      fragh a[4], b[2];
#pragma unroll
      for (int s = 0; s < 4; s++)
        a[s] = *(const fragh*)&As[bi][slab][wm + s * 16 + l15][quad * 8];
#pragma unroll
      for (int t = 0; t < 2; t++)
        b[t] = *(const fragh*)&Bs[bi][slab][wn + t * 16 + l15][quad * 8];
#pragma unroll
      for (int mi = 0; mi < 4; mi++)
#pragma unroll
        for (int ni = 0; ni < 2; ni++)
          acc[mi][ni] = __builtin_amdgcn_mfma_f32_16x16x32_f16(
              a[mi], b[ni], acc[mi][ni], 0, 0, 0);
    }
  };

  stage(0, 0);
#pragma unroll 1
  for (int t = 0; t < 15; ++t) {
    const int cur = t & 1;
    stage(cur ^ 1, (t + 1) << 6);
    __builtin_amdgcn_sched_barrier(0);
    asm volatile("s_waitcnt vmcnt(6)" ::: "memory");
    __builtin_amdgcn_sched_barrier(0);
    __builtin_amdgcn_s_barrier();
    compute(cur);
    __builtin_amdgcn_s_barrier();
  }
  __builtin_amdgcn_sched_barrier(0);
  asm volatile("s_waitcnt vmcnt(0)" ::: "memory");
  __builtin_amdgcn_sched_barrier(0);
  __builtin_amdgcn_s_barrier();
  compute(1);

#pragma unroll
  for (int mi = 0; mi < 4; mi++) {
    const int rbase = m0 + wm + mi * 16 + quad * 4;
#pragma unroll
    for (int ni = 0; ni < 2; ni++) {
      const int col = n0 + wn + ni * 16 + l15;
      const float bv_ = bo[col];
#pragma unroll
      for (int r = 0; r < 4; r++) {
        const int m = rbase + r;
        const float val =
            acc[mi][ni][r] + bv_ + resid[(size_t)m * 1024 + col];
        *(_Float16*)&yh[(size_t)m * 1024 + col] = (_Float16)val;
      }
    }
  }
}

// ---------------------------------------------------------------------------
// MFMA flash attention, fp16 (verified R11): window |j0-q0| <= 128, LDS-LUT
// softmax (fixed shift M=2), T14 async-STAGE (next K/V tile in registers
// during compute), s_setprio around MFMA clusters. 4 blocks/CU.
// ---------------------------------------------------------------------------
__global__ __launch_bounds__(256, 4) void attn2(
    const ush* __restrict__ qh, const ush* __restrict__ kh,
    const ush* __restrict__ vT, ush* __restrict__ ch) {
  __shared__ __align__(16) ush Kh[64][72];
  __shared__ __align__(16) ush VTs[64][72];   // [d][j]
  __shared__ __align__(16) ush Pst[64][72];   // [m][j]
  __shared__ float LUT[256];
  const int tid = threadIdx.x;
  const int lane = tid & 63, wave = tid >> 6;
  const int l15 = lane & 15, quad = lane >> 4;
  const int w16 = wave * 16;
  const int bh = blockIdx.y;
  const int b = bh >> 4, h = bh & 15;
  const int q0 = blockIdx.x * 64;

  const float K1 = 0.18033688011112042f;   // 0.125 * log2(e)
  const float K2 = 0.14426950408889634f;   // 0.1   * log2(e)
  {
    const float dd = (float)tid;
    LUT[tid] = __expf(-0.1f * fminf(dd, 5.0f)) * K1 - dd * K2
             - 2.8853900817779268f;        // 2*log2(e): fixed shift M=2
  }

  const size_t qrow = ((size_t)bh * S_ + q0 + w16 + l15) * D_;
  fragh a_h[2];
  a_h[0] = *(const fragh*)&qh[qrow + quad * 8];
  a_h[1] = *(const fragh*)&qh[qrow + 32 + quad * 8];

  f32x4 o[4];
  float lrow[4];
#pragma unroll
  for (int i = 0; i < 4; i++) {
    o[i] = (f32x4){0.f, 0.f, 0.f, 0.f};
    lrow[i] = 0.f;
  }

  const size_t kbase = (size_t)bh * S_ * D_;
  const size_t vbase = (size_t)bh * D_ * S_;

  const int jlo = (q0 > 128) ? q0 - 128 : 0;
  const int jend = (q0 + 192 < S_) ? q0 + 192 : S_;

  const int row0 = tid >> 3, dc0 = (tid & 7) * 8;
  const int row1 = (tid + 256) >> 3, dc1 = (tid & 7) * 8;

  uint4 kA0, kA1, vA0, vA1;
  uint4 kB0 = {0, 0, 0, 0}, kB1 = {0, 0, 0, 0};
  uint4 vB0 = {0, 0, 0, 0}, vB1 = {0, 0, 0, 0};
  kA0 = *(const uint4*)&kh[kbase + (size_t)(jlo + row0) * D_ + dc0];
  kA1 = *(const uint4*)&kh[kbase + (size_t)(jlo + row1) * D_ + dc1];
  vA0 = *(const uint4*)&vT[vbase + (size_t)row0 * S_ + jlo + dc0];
  vA1 = *(const uint4*)&vT[vbase + (size_t)row1 * S_ + jlo + dc1];

  for (int j0 = jlo; j0 < jend; j0 += 64) {
    __syncthreads();   // prev tile's frag reads done (also fences LUT fill)
    *(uint4*)&Kh[row0][dc0] = kA0;
    *(uint4*)&Kh[row1][dc1] = kA1;
    *(uint4*)&VTs[row0][dc0] = vA0;
    *(uint4*)&VTs[row1][dc1] = vA1;
    const int jn = j0 + 64;
    if (jn < jend) {   // async prefetch next tile into registers
      kB0 = *(const uint4*)&kh[kbase + (size_t)(jn + row0) * D_ + dc0];
      kB1 = *(const uint4*)&kh[kbase + (size_t)(jn + row1) * D_ + dc1];
      vB0 = *(const uint4*)&vT[vbase + (size_t)row0 * S_ + jn + dc0];
      vB1 = *(const uint4*)&vT[vbase + (size_t)row1 * S_ + jn + dc1];
    }
    __syncthreads();

    // ---- S = Q.K^T (single fp16 term) ----
    f32x4 c4[4];
#pragma unroll
    for (int nt = 0; nt < 4; nt++) c4[nt] = (f32x4){0.f, 0.f, 0.f, 0.f};
    __builtin_amdgcn_s_setprio(1);
#pragma unroll
    for (int kk = 0; kk < 2; kk++) {
#pragma unroll
      for (int nt = 0; nt < 4; nt++) {
        fragh bh_ = *(const fragh*)&Kh[nt * 16 + l15][kk * 32 + quad * 8];
        c4[nt] = __builtin_amdgcn_mfma_f32_16x16x32_f16(a_h[kk], bh_, c4[nt], 0, 0, 0);
      }
    }
    __builtin_amdgcn_s_setprio(0);

    // ---- LUT softmax + P store (C-layout: row=quad*4+r) ----
    const int ib = q0 + w16 + quad * 4 - j0 - l15;
#pragma unroll
    for (int r = 0; r < 4; r++) {
#pragma unroll
      for (int nt = 0; nt < 4; nt++) {
        int di = ib + r - nt * 16;
        di = (di < 0) ? -di : di;
        const float sv = exp2f(fmaf(c4[nt][r], K1, LUT[di]));
        lrow[r] += sv;
        *(_Float16*)&Pst[w16 + quad * 4 + r][nt * 16 + l15] = (_Float16)sv;
      }
    }

    // ---- PV (own rows only; same-wave LDS ordering, no barrier) ----
    fragh pa[2];
    pa[0] = *(const fragh*)&Pst[w16 + l15][quad * 8];
    pa[1] = *(const fragh*)&Pst[w16 + l15][32 + quad * 8];
    __builtin_amdgcn_s_setprio(1);
#pragma unroll
    for (int dt = 0; dt < 4; dt++) {
      fragh vb0 = *(const fragh*)&VTs[dt * 16 + l15][quad * 8];
      fragh vb1 = *(const fragh*)&VTs[dt * 16 + l15][32 + quad * 8];
      o[dt] = __builtin_amdgcn_mfma_f32_16x16x32_f16(pa[0], vb0, o[dt], 0, 0, 0);
      o[dt] = __builtin_amdgcn_mfma_f32_16x16x32_f16(pa[1], vb1, o[dt], 0, 0, 0);
    }
    __builtin_amdgcn_s_setprio(0);

    kA0 = kB0; kA1 = kB1; vA0 = vB0; vA1 = vB1;
  }

  // ---- deferred row-sum reduction + normalize + write fp16 ctx ----
#pragma unroll
  for (int r = 0; r < 4; r++) {
#pragma unroll
    for (int off = 1; off < 16; off <<= 1) lrow[r] += __shfl_xor(lrow[r], off);
    const float inv = 1.0f / lrow[r];
    const size_t rowp =
        ((size_t)(b * S_ + q0 + w16 + quad * 4 + r)) * H_ + h * 64;
#pragma unroll
    for (int dt = 0; dt < 4; dt++)
      *(_Float16*)&ch[rowp + dt * 16 + l15] = (_Float16)(o[dt][r] * inv);
  }
}

// ---------------------------------------------------------------------------
// Fused LayerNorm + span logits, wave-per-row (no barriers). (verified R10)
// ---------------------------------------------------------------------------
__global__ __launch_bounds__(256) void ln_span(
    const ush* __restrict__ yh, const float* __restrict__ g,
    const float* __restrict__ bta, const float* __restrict__ WsT,
    const float* __restrict__ bs, float* __restrict__ logits) {
  const int tid = threadIdx.x, lane = tid & 63, wave = tid >> 6;
  const int row = blockIdx.x * 4 + wave;
  const int h0 = lane * 16;
  const ush* yr = yh + (size_t)row * 1024 + h0;

  fragh v0 = *(const fragh*)yr;
  fragh v1 = *(const fragh*)(yr + 8);
  float v[16];
#pragma unroll
  for (int u = 0; u < 8; u++) { v[u] = (float)v0[u]; v[8 + u] = (float)v1[u]; }

  float s = 0.f, s2 = 0.f;
#pragma unroll
  for (int u = 0; u < 16; u++) { s += v[u]; s2 += v[u] * v[u]; }
#pragma unroll
  for (int off = 32; off; off >>= 1) {
    s += __shfl_xor(s, off);
    s2 += __shfl_xor(s2, off);
  }
  const float mu = s * (1.0f / 1024.0f);
  const float var = s2 * (1.0f / 1024.0f) - mu * mu;
  const float inv = rsqrtf(var + 1e-5f);

  float yn[16];
#pragma unroll
  for (int i = 0; i < 4; i++) {
    float4 gg = *(const float4*)&g[h0 + i * 4];
    float4 bb = *(const float4*)&bta[h0 + i * 4];
    yn[i * 4 + 0] = (v[i * 4 + 0] - mu) * inv * gg.x + bb.x;
    yn[i * 4 + 1] = (v[i * 4 + 1] - mu) * inv * gg.y + bb.y;
    yn[i * 4 + 2] = (v[i * 4 + 2] - mu) * inv * gg.z + bb.z;
    yn[i * 4 + 3] = (v[i * 4 + 3] - mu) * inv * gg.w + bb.w;
  }

  float lg[9];
#pragma unroll
  for (int l = 0; l < 9; l++) {
    float acc = 0.f;
#pragma unroll
    for (int i = 0; i < 4; i++) {
      float4 w4 = *(const float4*)&WsT[l * 1024 + h0 + i * 4];
      acc += yn[i * 4 + 0] * w4.x + yn[i * 4 + 1] * w4.y +
             yn[i * 4 + 2] * w4.z + yn[i * 4 + 3] * w4.w;
    }
    lg[l] = acc;
  }
#pragma unroll
  for (int l = 0; l < 9; l++) {
#pragma unroll
    for (int off = 32; off; off >>= 1) lg[l] += __shfl_xor(lg[l], off);
  }
  if (lane == 0) {
#pragma unroll
    for (int l = 0; l < 9; l++)
      logits[(size_t)row * 9 + l] = lg[l] + bs[l];
  }
}

// ---------------------------------------------------------------------------
// Entity-bias adjustment + FP32 output. One thread per token.
// ---------------------------------------------------------------------------
__global__ __launch_bounds__(256) void final_kernel(
    const float* __restrict__ logits, const float* __restrict__ eb,
    float* __restrict__ out) {
  const int m = blockIdx.x * 256 + threadIdx.x;
  const int i = m & 1023;
  float cur[9];
#pragma unroll
  for (int l = 0; l < 9; l++) cur[l] = logits[(size_t)m * 9 + l];
  if (i > 0) {
    const float* prev = logits + (size_t)(m - 1) * 9;
    int am = 0;
    float best = prev[0];
#pragma unroll
    for (int l = 1; l < 9; l++) {
      float pv = prev[l];
      if (pv > best) { best = pv; am = l; }
    }
    if (am == 1) cur[2] += 2.0f * eb[2];
  }
#pragma unroll
  for (int l = 0; l < 9; l++) out[(size_t)m * 9 + l] = cur[l];
}

// ---------------------------------------------------------------------------
extern "C" void kernel_launch(void* const* d_in, const int* in_sizes, int n_in,
                              void* d_out, int out_size, void* d_ws, size_t ws_size,
                              hipStream_t stream) {
  const float* x    = (const float*)d_in[0];
  const float* Wq   = (const float*)d_in[1];
  const float* bq   = (const float*)d_in[2];
  const float* Wk   = (const float*)d_in[3];
  const float* bk   = (const float*)d_in[4];
  const float* Wv   = (const float*)d_in[5];
  const float* bv   = (const float*)d_in[6];
  const float* Wo   = (const float*)d_in[7];
  const float* bo   = (const float*)d_in[8];
  const float* ln_g = (const float*)d_in[9];
  const float* ln_b = (const float*)d_in[10];
  const float* Ws   = (const float*)d_in[11];
  const float* bs   = (const float*)d_in[12];
  const float* eb   = (const float*)d_in[13];
  float* out = (float*)d_out;
  char* W8 = (char*)d_ws;

  // ---- ws layout (fp16 everywhere; 64 MB envelope) ----
  ush* WoT  = (ush*)(W8 + 0 * MB_);
  ush* WqT  = (ush*)(W8 + 2 * MB_);
  ush* WkT  = (ush*)(W8 + 4 * MB_);
  ush* WvT  = (ush*)(W8 + 6 * MB_);
  ush* xh   = (ush*)(W8 + 8 * MB_);
  ush* qh   = (ush*)(W8 + 16 * MB_);
  ush* kh   = (ush*)(W8 + 24 * MB_);
  ush* vT   = (ush*)(W8 + 32 * MB_);
  ush* ctxh = (ush*)(W8 + 40 * MB_);
  ush* yh   = (ush*)(W8 + 48 * MB_);
  float* lg_ws = (float*)(W8 + 56 * MB_);
  float* WsT   = (float*)(W8 + 60 * MB_);

  prep<<<3073, 256, 0, stream>>>(
      x, Wq, Wk, Wv, Wo, Ws, xh, WqT, WkT, WvT, WoT, WsT);

  gemm_qkv<<<dim3(8, 32, 3), 256, 0, stream>>>(
      xh, WqT, WkT, WvT, bq, bk, bv, qh, kh, vT);
  attn2<<<dim3(16, 64), 256, 0, stream>>>(qh, kh, vT, ctxh);
  gemm_o<<<dim3(16, 32), 256, 0, stream>>>(ctxh, WoT, bo, x, yh);
  ln_span<<<1024, 256, 0, stream>>>(yh, ln_g, ln_b, WsT, bs, lg_ws);
  final_kernel<<<16, 256, 0, stream>>>(lg_ws, eb, out);
}